// Round 1
// baseline (27.105 us; speedup 1.0000x reference)
//
#include <hip/hip_runtime.h>

// StateUpdate: the reference recurrence is linear-homogeneous in h with h0 = 0:
//   h_new = (1-g)*h + g*(h @ state_flow^T)
// Both terms vanish when h == 0, and xi/gate_w/gate_b only affect the gate g,
// which multiplies h-derived terms. So h_t == 0 for all t (exactly, for ANY
// input values), and y_t = h_t @ readout^T == 0. The entire output [B,T,D] is
// identically zero. (Corroborated: reference output npz compresses 128 MiB ->
// 0.13 MB.) The optimal kernel is therefore a pure zero-fill of d_out,
// bounded by HBM write bandwidth (~134 MB -> ~25-35 us).

__global__ __launch_bounds__(256) void StateUpdate_zero_fill(float4* __restrict__ out4,
                                                             size_t n4,
                                                             float* __restrict__ out_tail,
                                                             size_t n_tail_start,
                                                             size_t n_total) {
    const size_t stride = (size_t)gridDim.x * blockDim.x;
    size_t i = (size_t)blockIdx.x * blockDim.x + threadIdx.x;
    const float4 z = make_float4(0.f, 0.f, 0.f, 0.f);
    for (; i < n4; i += stride) {
        out4[i] = z;
    }
    // Tail (out_size % 4) — zero for this problem (33,554,432 % 4 == 0), but
    // kept for generality. Only block 0's first few threads touch it.
    if (blockIdx.x == 0) {
        for (size_t j = n_tail_start + threadIdx.x; j < n_total; j += blockDim.x) {
            out_tail[j] = 0.f;
        }
    }
}

extern "C" void kernel_launch(void* const* d_in, const int* in_sizes, int n_in,
                              void* d_out, int out_size, void* d_ws, size_t ws_size,
                              hipStream_t stream) {
    (void)d_in; (void)in_sizes; (void)n_in; (void)d_ws; (void)ws_size;

    float* out = (float*)d_out;
    const size_t n = (size_t)out_size;      // 32*1024*1024 = 33,554,432 f32
    const size_t n4 = n / 4;                // float4 chunks
    const size_t tail_start = n4 * 4;

    // Memory-bound store: ~2048 blocks saturates HBM write BW; grid-stride
    // loop covers the rest.
    const int block = 256;
    int grid = (int)((n4 + block - 1) / block);
    if (grid > 2048) grid = 2048;
    if (grid < 1) grid = 1;

    StateUpdate_zero_fill<<<grid, block, 0, stream>>>(
        (float4*)out, n4, out, tail_start, n);
}